// Round 7
// baseline (367.409 us; speedup 1.0000x reference)
//
#include <hip/hip_runtime.h>
#include <math.h>

// Quantum dense layer, 12 qubits, DEPTH=1.  v3: DS-pipe pressure relief.
// v1 (90us): 1 wave/row, latency-bound (Occ 19%, VALU 27%).
// v2 (~44us est): 4 waves/row. Estimated DS-pipe-bound: ~340 DS instr/wave
//   (192 shfl->ds_bpermute + 128 b32 exchange) ~= 26us serialized per CU.
// v3 changes (structure/math identical to v2, absmax 7.6e-6 validated):
//   - lane-wire mask 1,2  -> DPP quad_perm 0xB1/0x4E (VALU pipe)
//   - lane-wire mask 4,8,16 -> explicit ds_swizzle 0x101F/0x201F/0x401F
//   - lane-wire mask 32   -> v_permlane32_swap (VALU pipe) + cndmask
//   - wave-wire exchange  -> float2 (b64) packed: 128 -> 64 DS instr
// DS per wave ~340 -> ~150; 96 ops move to the 4x-wider VALU pipes.

#define EPSF 1e-10f

typedef unsigned uv2 __attribute__((ext_vector_type(2)));

// partner value at lane^  (1<<pb), pb compile-time constant under full unroll
__device__ __forceinline__ float lane_partner(float v, const int pb, const bool hihalf) {
    if (pb == 0)  // xor 1: quad_perm [1,0,3,2]
        return __int_as_float(__builtin_amdgcn_update_dpp(
            0, __float_as_int(v), 0xB1, 0xF, 0xF, true));
    if (pb == 1)  // xor 2: quad_perm [2,3,0,1]
        return __int_as_float(__builtin_amdgcn_update_dpp(
            0, __float_as_int(v), 0x4E, 0xF, 0xF, true));
    if (pb == 2)  // xor 4
        return __int_as_float(__builtin_amdgcn_ds_swizzle(__float_as_int(v), 0x101F));
    if (pb == 3)  // xor 8
        return __int_as_float(__builtin_amdgcn_ds_swizzle(__float_as_int(v), 0x201F));
    if (pb == 4)  // xor 16
        return __int_as_float(__builtin_amdgcn_ds_swizzle(__float_as_int(v), 0x401F));
    // pb == 5: xor 32 via permlane32_swap. With (x,x): r[0]={x.lo,x.lo},
    // r[1]={x.hi,x.hi}  =>  partner = lane<32 ? r[1] : r[0].
    uv2 r = __builtin_amdgcn_permlane32_swap(
        __float_as_uint(v), __float_as_uint(v), false, false);
    return __uint_as_float(hihalf ? r[0] : r[1]);
}

__global__ __launch_bounds__(256, 8) void qdense_kernel(
    const float* __restrict__ x,
    const float* __restrict__ qw,
    float* __restrict__ out)
{
    __shared__ __align__(16) float buf[4096];   // 16 KB, reused: exchange (as float2) + prob staging
    __shared__ float bsum[4];

    const int tid = threadIdx.x;
    const int w   = tid >> 6;     // wave id   = state bits 7:6 (wires 4,5)
    const int ln  = tid & 63;     // lane      = state bits 5:0 (wires 6..11)
    const int row = blockIdx.x;
    const bool hihalf = (ln >= 32);

    const float* __restrict__ xr = x + ((size_t)row << 12);

    float ar[16], ai[16];         // register index l = state bits 11:8 (wires 0..3)

    // ---- load + block squared-norm ----
    float ss = 0.f;
    const int wl = (w << 6) | ln;
#pragma unroll
    for (int l = 0; l < 16; ++l) {
        const float v = xr[(l << 8) | wl];   // per-wave 256B contiguous: coalesced
        ar[l] = v;
        ss = fmaf(v, v, ss);
    }
#pragma unroll
    for (int m = 32; m; m >>= 1) ss += __shfl_xor(ss, m, 64);
    if (ln == 0) bsum[w] = ss;
    __syncthreads();
    const float ss_tot = bsum[0] + bsum[1] + bsum[2] + bsum[3];

    const float nrm = sqrtf(ss_tot);
    if (nrm > EPSF) {
        const float inv = 1.0f / nrm;
#pragma unroll
        for (int l = 0; l < 16; ++l) ar[l] *= inv;
    } else {
#pragma unroll
        for (int l = 0; l < 16; ++l) ar[l] = 0.015625f;   // 1/sqrt(4096)
    }
#pragma unroll
    for (int l = 0; l < 16; ++l) ai[l] = 0.f;

    // ---- register wires (0..3) and lane wires (6..11) ----
    // U = [[p - iq, -r - it], [r - it, p + iq]]  (validated v1/v2)
#pragma unroll
    for (int wq = 0; wq < 12; ++wq) {
        if (wq == 4 || wq == 5) continue;          // wave wires handled after
        const float phi = qw[wq * 3 + 0];
        const float th  = qw[wq * 3 + 1];
        const float om  = qw[wq * 3 + 2];
        const float c = __cosf(0.5f * th), s = __sinf(0.5f * th);
        const float A = 0.5f * (phi + om), B = 0.5f * (phi - om);
        const float p = c * __cosf(A), q = c * __sinf(A);
        const float r = s * __cosf(B), t = s * __sinf(B);

        const int pb = 11 - wq;                    // state bit of this wire
        if (pb >= 8) {
            // register-local: pair (l0, l0|bit)
            const int bit = 1 << (pb - 8);
#pragma unroll
            for (int l0 = 0; l0 < 16; ++l0) {
                if (l0 & bit) continue;
                const int l1 = l0 | bit;
                const float a0r = ar[l0], a0i = ai[l0];
                const float a1r = ar[l1], a1i = ai[l1];
                ar[l0] =  p * a0r + q * a0i - r * a1r + t * a1i;
                ai[l0] = -q * a0r + p * a0i - t * a1r - r * a1i;
                ar[l1] =  r * a0r + t * a0i + p * a1r - q * a1i;
                ai[l1] = -t * a0r + r * a0i + q * a1r + p * a1i;
            }
        } else {
            // lane wire: partner lane = ln ^ (1<<pb); pb is 0..5 compile-time
            const int side = (ln >> pb) & 1;
            const float sq = side ? -q : q;
            const float sr = side ? r : -r;
#pragma unroll
            for (int l = 0; l < 16; ++l) {
                const float pr = lane_partner(ar[l], pb, hihalf);
                const float pi = lane_partner(ai[l], pb, hihalf);
                const float mr = ar[l], mi = ai[l];
                ar[l] = p * mr + sq * mi + sr * pr + t * pi;
                ai[l] = p * mi - sq * mr - t * pr + sr * pi;
            }
        }
    }

    // ---- wave wires (4,5): LDS exchange, float2-packed (b64), 2 chunks ----
    float2* __restrict__ B2 = reinterpret_cast<float2*>(buf);
#pragma unroll
    for (int wq = 4; wq <= 5; ++wq) {
        const float phi = qw[wq * 3 + 0];
        const float th  = qw[wq * 3 + 1];
        const float om  = qw[wq * 3 + 2];
        const float c = __cosf(0.5f * th), s = __sinf(0.5f * th);
        const float A = 0.5f * (phi + om), B = 0.5f * (phi - om);
        const float p = c * __cosf(A), q = c * __sinf(A);
        const float r = s * __cosf(B), t = s * __sinf(B);

        const int wmask = (wq == 4) ? 2 : 1;       // wire4 -> w bit1, wire5 -> w bit0
        const int side  = (w & wmask) ? 1 : 0;     // uniform per wave: no divergence
        const float sq = side ? -q : q;
        const float sr = side ? r : -r;
        const int pw = w ^ wmask;
#pragma unroll
        for (int c2 = 0; c2 < 2; ++c2) {
            __syncthreads();                       // buffer free (prior reads done)
#pragma unroll
            for (int rr = 0; rr < 8; ++rr) {
                const int l = (c2 << 3) | rr;
                B2[(w << 9) | (rr << 6) | ln] = make_float2(ar[l], ai[l]);  // b64, 2-way bank alias (free)
            }
            __syncthreads();
#pragma unroll
            for (int rr = 0; rr < 8; ++rr) {
                const int l = (c2 << 3) | rr;
                const float2 pp = B2[(pw << 9) | (rr << 6) | ln];
                const float mr = ar[l], mi = ai[l];
                ar[l] = p * mr + sq * mi + sr * pp.x + t * pp.y;
                ai[l] = p * mi - sq * mr - t * pp.x + sr * pp.y;
            }
        }
    }

    // ---- probs + block sum + Gray scatter ----
    float p2[16];
    float s2 = 0.f;
#pragma unroll
    for (int l = 0; l < 16; ++l) {
        p2[l] = fmaf(ar[l], ar[l], ai[l] * ai[l]);
        s2 += p2[l];
    }
#pragma unroll
    for (int m = 32; m; m >>= 1) s2 += __shfl_xor(s2, m, 64);

    __syncthreads();                               // protect last exchange reads
    if (ln == 0) bsum[w] = s2;
#pragma unroll
    for (int l = 0; l < 16; ++l) {
        const int sdx = (l << 8) | (w << 6) | ln;
        buf[sdx ^ (sdx >> 1)] = p2[l];             // CNOT cascade = Gray remap; ~2-way bank alias (free)
    }
    __syncthreads();

    const float ps = bsum[0] + bsum[1] + bsum[2] + bsum[3];
    float* __restrict__ orow = out + ((size_t)row << 12);
    if (ps > EPSF) {
        const float sc = 1.0f / ps;
#pragma unroll
        for (int v = 0; v < 4; ++v) {
            const int k = (w << 10) | (v << 8) | (ln << 2);
            float4 d = *reinterpret_cast<const float4*>(&buf[k]);
            d.x *= sc; d.y *= sc; d.z *= sc; d.w *= sc;
            *reinterpret_cast<float4*>(&orow[k]) = d;
        }
    } else {
        const float u = 1.0f / 4096.0f;
        const float4 d = make_float4(u, u, u, u);
#pragma unroll
        for (int v = 0; v < 4; ++v) {
            const int k = (w << 10) | (v << 8) | (ln << 2);
            *reinterpret_cast<float4*>(&orow[k]) = d;
        }
    }
}

extern "C" void kernel_launch(void* const* d_in, const int* in_sizes, int n_in,
                              void* d_out, int out_size, void* d_ws, size_t ws_size,
                              hipStream_t stream) {
    const float* x  = (const float*)d_in[0];   // (2048, 4096) f32
    const float* qw = (const float*)d_in[1];   // (1, 12, 3) f32
    float* out = (float*)d_out;                // (2048, 4096) f32
    qdense_kernel<<<2048, 256, 0, stream>>>(x, qw, out);
}

// Round 8
// 119.159 us; speedup vs baseline: 3.0834x; 3.0834x over previous
//
#include <hip/hip_runtime.h>
#include <math.h>

// Quantum dense layer, 12 qubits, DEPTH=1.  v4: transpose instead of shuffles.
// History: v1 90us (1 wave/row, latency-bound); v2 ~44us (4 waves/row,
// DS-pipe-bound ~340 DS instr/wave); v3 302us REGRESSION (spill: VGPR cap 64
// from launch_bounds(256,8), 1.1GB scratch traffic) — but v3 validated DPP /
// swizzle / permlane semantics (passed).
// v4: launch_bounds(256,4) (VGPR cap 128, no spill; 16 waves/CU saturates DS)
//  - wires 0-3  : reg-local (state bits 11:8)
//  - wires 10,11: DPP quad_perm 0x4E/0xB1 (VALU pipe, v3-validated)
//  - wires 6-9  : ONE full-state LDS transpose (swap s[11:8]<->s[5:2], XOR-
//                 swizzled both sides, conflict-free) makes them reg-local
//  - wires 4,5  : float2 LDS exchange across waves (v2/v3-validated)
//  - epilogue   : Gray scatter with XOR swizzle (2-way = free), linear read
//                 applies the same XOR. DS/wave ~350 -> ~130, bpermute -> 0.

#define EPSF 1e-10f

__device__ __forceinline__ float dpp_xor1(float v) {   // partner at lane^1
    return __int_as_float(__builtin_amdgcn_update_dpp(
        0, __float_as_int(v), 0xB1, 0xF, 0xF, true));  // quad_perm [1,0,3,2]
}
__device__ __forceinline__ float dpp_xor2(float v) {   // partner at lane^2
    return __int_as_float(__builtin_amdgcn_update_dpp(
        0, __float_as_int(v), 0x4E, 0xF, 0xF, true));  // quad_perm [2,3,0,1]
}

__global__ __launch_bounds__(256, 4) void qdense_kernel(
    const float* __restrict__ x,
    const float* __restrict__ qw,
    float* __restrict__ out)
{
    __shared__ __align__(16) float buf[8192];   // 32 KB: transpose/exchange (float2) + prob staging
    __shared__ float bsum[4];

    const int tid = threadIdx.x;
    const int w   = tid >> 6;     // state bits 7:6 (wires 4,5)
    const int ln  = tid & 63;     // state bits 5:0
    const int row = blockIdx.x;

    const float* __restrict__ xr = x + ((size_t)row << 12);

    float ar[16], ai[16];         // layout 1: reg l = state bits 11:8 (wires 0..3)

    // ---- load + block squared-norm ----
    float ss = 0.f;
    const int wl = (w << 6) | ln;
#pragma unroll
    for (int l = 0; l < 16; ++l) {
        const float v = xr[(l << 8) | wl];   // 256B contiguous per instr
        ar[l] = v;
        ss = fmaf(v, v, ss);
    }
#pragma unroll
    for (int m = 32; m; m >>= 1) ss += __shfl_xor(ss, m, 64);
    if (ln == 0) bsum[w] = ss;
    __syncthreads();
    const float ss_tot = bsum[0] + bsum[1] + bsum[2] + bsum[3];

    const float nrm = sqrtf(ss_tot);
    if (nrm > EPSF) {
        const float inv = 1.0f / nrm;
#pragma unroll
        for (int l = 0; l < 16; ++l) ar[l] *= inv;
    } else {
#pragma unroll
        for (int l = 0; l < 16; ++l) ar[l] = 0.015625f;   // 1/sqrt(4096)
    }
#pragma unroll
    for (int l = 0; l < 16; ++l) ai[l] = 0.f;

    // U = [[p - iq, -r - it], [r - it, p + iq]]  (validated v1..v3)
#define COEFFS(wq)                                                   \
    const float phi = qw[(wq) * 3 + 0];                              \
    const float th  = qw[(wq) * 3 + 1];                              \
    const float om  = qw[(wq) * 3 + 2];                              \
    const float c = __cosf(0.5f * th), s = __sinf(0.5f * th);        \
    const float A = 0.5f * (phi + om), Bb = 0.5f * (phi - om);       \
    const float p = c * __cosf(A), q = c * __sinf(A);                \
    const float r = s * __cosf(Bb), t = s * __sinf(Bb);

    // ---- wires 0..3: reg-local in layout 1 (pair mask 8,4,2,1 on l) ----
#pragma unroll
    for (int wq = 0; wq < 4; ++wq) {
        COEFFS(wq);
        const int bit = 1 << (3 - wq);
#pragma unroll
        for (int l0 = 0; l0 < 16; ++l0) {
            if (l0 & bit) continue;
            const int l1 = l0 | bit;
            const float a0r = ar[l0], a0i = ai[l0];
            const float a1r = ar[l1], a1i = ai[l1];
            ar[l0] =  p * a0r + q * a0i - r * a1r + t * a1i;
            ai[l0] = -q * a0r + p * a0i - t * a1r - r * a1i;
            ar[l1] =  r * a0r + t * a0i + p * a1r - q * a1i;
            ai[l1] = -t * a0r + r * a0i + q * a1r + p * a1i;
        }
    }

    // ---- wires 10,11: DPP (state bits 1,0) ----
#pragma unroll
    for (int wq = 10; wq <= 11; ++wq) {
        COEFFS(wq);
        const int pb = 11 - wq;                 // 1 or 0
        const int side = (ln >> pb) & 1;
        const float sq = side ? -q : q;
        const float sr = side ? r : -r;
#pragma unroll
        for (int l = 0; l < 16; ++l) {
            const float pr = (pb == 0) ? dpp_xor1(ar[l]) : dpp_xor2(ar[l]);
            const float pi = (pb == 0) ? dpp_xor1(ai[l]) : dpp_xor2(ai[l]);
            const float mr = ar[l], mi = ai[l];
            ar[l] = p * mr + sq * mi + sr * pr + t * pi;
            ai[l] = p * mi - sq * mr - t * pr + sr * pi;
        }
    }

    // ---- transpose: swap state bits [11:8] <-> [5:2] (XOR-swizzled) ----
    float2* __restrict__ B2 = reinterpret_cast<float2*>(buf);
#pragma unroll
    for (int l = 0; l < 16; ++l)
        B2[(l << 8) | (w << 6) | (ln ^ (l << 2))] = make_float2(ar[l], ai[l]);
    __syncthreads();
    {
        const int lo = (ln >> 2) & 15;          // old reg index now in lane bits
#pragma unroll
        for (int l2 = 0; l2 < 16; ++l2) {
            const int la = ((l2 << 2) | (ln & 3)) ^ (lo << 2);
            const float2 v = B2[(lo << 8) | (w << 6) | la];
            ar[l2] = v.x; ai[l2] = v.y;
        }
    }
    // layout 2: thread(w,ln), reg l2 holds amp s:
    //   s = ((ln>>2)&15)<<8 | w<<6 | l2<<2 | (ln&3)

    // ---- wires 6..9: now reg-local (pair mask 8,4,2,1 on l2) ----
#pragma unroll
    for (int wq = 6; wq < 10; ++wq) {
        COEFFS(wq);
        const int bit = 1 << (9 - wq);
#pragma unroll
        for (int l0 = 0; l0 < 16; ++l0) {
            if (l0 & bit) continue;
            const int l1 = l0 | bit;
            const float a0r = ar[l0], a0i = ai[l0];
            const float a1r = ar[l1], a1i = ai[l1];
            ar[l0] =  p * a0r + q * a0i - r * a1r + t * a1i;
            ai[l0] = -q * a0r + p * a0i - t * a1r - r * a1i;
            ar[l1] =  r * a0r + t * a0i + p * a1r - q * a1i;
            ai[l1] = -t * a0r + r * a0i + q * a1r + p * a1i;
        }
    }

    // ---- wires 4,5: cross-wave float2 exchange (w bits unchanged) ----
#pragma unroll
    for (int wq = 4; wq <= 5; ++wq) {
        COEFFS(wq);
        const int wmask = (wq == 4) ? 2 : 1;
        const int side  = (w & wmask) ? 1 : 0;   // uniform per wave
        const float sq = side ? -q : q;
        const float sr = side ? r : -r;
        const int pw = w ^ wmask;
        __syncthreads();                         // prior buf reads done
#pragma unroll
        for (int l = 0; l < 16; ++l)
            B2[(l << 8) | (w << 6) | ln] = make_float2(ar[l], ai[l]);
        __syncthreads();
#pragma unroll
        for (int l = 0; l < 16; ++l) {
            const float2 pp = B2[(l << 8) | (pw << 6) | ln];
            const float mr = ar[l], mi = ai[l];
            ar[l] = p * mr + sq * mi + sr * pp.x + t * pp.y;
            ai[l] = p * mi - sq * mr - t * pp.x + sr * pp.y;
        }
    }

    // ---- probs + sum + Gray scatter (swizzled: 2-way, free) ----
    float p2[16];
    float s2 = 0.f;
#pragma unroll
    for (int l = 0; l < 16; ++l) {
        p2[l] = fmaf(ar[l], ar[l], ai[l] * ai[l]);
        s2 += p2[l];
    }
#pragma unroll
    for (int m = 32; m; m >>= 1) s2 += __shfl_xor(s2, m, 64);

    __syncthreads();                             // exchange reads done before reuse
    if (ln == 0) bsum[w] = s2;
    {
        const int hi = ((ln >> 2) & 15) << 8;
#pragma unroll
        for (int l2 = 0; l2 < 16; ++l2) {
            const int sdx = hi | (w << 6) | (l2 << 2) | (ln & 3);
            const int g   = sdx ^ (sdx >> 1);    // CNOT cascade = Gray remap
            buf[g ^ (((g >> 8) & 7) << 2)] = p2[l2];
        }
    }
    __syncthreads();

    const float ps = bsum[0] + bsum[1] + bsum[2] + bsum[3];
    float* __restrict__ orow = out + ((size_t)row << 12);
    if (ps > EPSF) {
        const float sc = 1.0f / ps;
#pragma unroll
        for (int v = 0; v < 4; ++v) {
            const int k   = (w << 10) | (v << 8) | (ln << 2);
            const int idx = k ^ (((k >> 8) & 7) << 2);   // same XOR as scatter
            float4 d = *reinterpret_cast<const float4*>(&buf[idx]);
            d.x *= sc; d.y *= sc; d.z *= sc; d.w *= sc;
            *reinterpret_cast<float4*>(&orow[k]) = d;
        }
    } else {
        const float u = 1.0f / 4096.0f;
        const float4 d = make_float4(u, u, u, u);
#pragma unroll
        for (int v = 0; v < 4; ++v) {
            const int k = (w << 10) | (v << 8) | (ln << 2);
            *reinterpret_cast<float4*>(&orow[k]) = d;
        }
    }
}

extern "C" void kernel_launch(void* const* d_in, const int* in_sizes, int n_in,
                              void* d_out, int out_size, void* d_ws, size_t ws_size,
                              hipStream_t stream) {
    const float* x  = (const float*)d_in[0];   // (2048, 4096) f32
    const float* qw = (const float*)d_in[1];   // (1, 12, 3) f32
    float* out = (float*)d_out;                // (2048, 4096) f32
    qdense_kernel<<<2048, 256, 0, stream>>>(x, qw, out);
}

// Round 10
// 105.979 us; speedup vs baseline: 3.4668x; 1.1244x over previous
//
#include <hip/hip_runtime.h>
#include <math.h>

// Quantum dense layer, 12 qubits, DEPTH=1.  v5 = v4 structure + v2 occupancy + packed fp32.
// History: v1 90us (1 wave/row, latency-bound). v2 ~44us (4 waves/row, 16KB LDS,
//   32 waves/CU, DS-heavy: 340 DS/wave). v3 302us (spill disaster at 64-VGPR cap).
//   v4 55us (transpose kills bpermutes, DS ~130/wave, BUT 33KB LDS -> 16 waves/CU).
// v5: all LDS phases chunked through ONE 16 KB buffer -> 8 blocks/CU (32 waves/CU),
//   transpose chunked by wave-pairs (whole-wave granularity, no EXEC waste),
//   complex state as float2 with v_pk_fma_f32 butterflies (VALU issue halved),
//   p2[] array eliminated (peak live ~52 VGPR < 64 cap).

#define EPSF 1e-10f

typedef float f32x2 __attribute__((ext_vector_type(2)));

__device__ __forceinline__ float dpp_xor1(float v) {   // partner at lane^1
    return __int_as_float(__builtin_amdgcn_update_dpp(
        0, __float_as_int(v), 0xB1, 0xF, 0xF, true));  // quad_perm [1,0,3,2]
}
__device__ __forceinline__ float dpp_xor2(float v) {   // partner at lane^2
    return __int_as_float(__builtin_amdgcn_update_dpp(
        0, __float_as_int(v), 0x4E, 0xF, 0xF, true));  // quad_perm [2,3,0,1]
}
__device__ __forceinline__ f32x2 swp(f32x2 v) { return f32x2{v.y, v.x}; }
__device__ __forceinline__ f32x2 pkfma(f32x2 a, f32x2 b, f32x2 c) {
    return __builtin_elementwise_fma(a, b, c);         // -> v_pk_fma_f32
}

__global__ __launch_bounds__(256, 8) void qdense_kernel(
    const float* __restrict__ x,
    const float* __restrict__ qw,
    float* __restrict__ out)
{
    __shared__ __align__(16) float buf[4096];   // 16 KB, reused: f32x2[2048] staging + float[4096] probs
    __shared__ float bsum[4];
    f32x2* __restrict__ B2 = reinterpret_cast<f32x2*>(buf);

    const int tid = threadIdx.x;
    const int w   = tid >> 6;     // state bits 7:6 (wires 4,5)
    const int ln  = tid & 63;     // state bits 5:0
    const int row = blockIdx.x;

    const float* __restrict__ xr = x + ((size_t)row << 12);

    f32x2 a[16];                  // layout 1: reg l = state bits 11:8 (wires 0..3)

    // ---- load + block squared-norm ----
    float ss = 0.f;
    const int wl = (w << 6) | ln;
#pragma unroll
    for (int l = 0; l < 16; ++l) {
        const float v = xr[(l << 8) | wl];   // 256B contiguous per instr
        a[l].x = v; a[l].y = 0.f;
        ss = fmaf(v, v, ss);
    }
#pragma unroll
    for (int m = 32; m; m >>= 1) ss += __shfl_xor(ss, m, 64);
    if (ln == 0) bsum[w] = ss;
    __syncthreads();
    const float ss_tot = bsum[0] + bsum[1] + bsum[2] + bsum[3];

    const float nrm = sqrtf(ss_tot);
    if (nrm > EPSF) {
        const float inv = 1.0f / nrm;
#pragma unroll
        for (int l = 0; l < 16; ++l) a[l].x *= inv;
    } else {
#pragma unroll
        for (int l = 0; l < 16; ++l) a[l].x = 0.015625f;   // 1/sqrt(4096)
    }

    // U = [[p - iq, -r - it], [r - it, p + iq]]  (validated v1..v4)
#define COEFFS(wq)                                                   \
    const float phi = qw[(wq) * 3 + 0];                              \
    const float th  = qw[(wq) * 3 + 1];                              \
    const float om  = qw[(wq) * 3 + 2];                              \
    const float c = __cosf(0.5f * th), s = __sinf(0.5f * th);        \
    const float A = 0.5f * (phi + om), Bb = 0.5f * (phi - om);       \
    const float p = c * __cosf(A), q = c * __sinf(A);                \
    const float r = s * __cosf(Bb), t = s * __sinf(Bb);

    // ---- wires 0..3: reg-local, packed butterflies ----
    // out0 = P.u0 + Q.swp(u0) + Rm.u1 + T.swp(u1); out1 = R.u0 + T.swp(u0) + P.u1 + Qm.swp(u1)
#pragma unroll
    for (int wq = 0; wq < 4; ++wq) {
        COEFFS(wq);
        const f32x2 P={p,p}, Q={q,-q}, Qm={-q,q}, R={r,r}, Rm={-r,-r}, T={t,-t};
        const int bit = 1 << (3 - wq);
#pragma unroll
        for (int l0 = 0; l0 < 16; ++l0) {
            if (l0 & bit) continue;
            const int l1 = l0 | bit;
            const f32x2 u0 = a[l0], u1 = a[l1], s0 = swp(u0), s1 = swp(u1);
            a[l0] = pkfma(P, u0, pkfma(Q, s0, pkfma(Rm, u1, T * s1)));
            a[l1] = pkfma(R, u0, pkfma(T, s0, pkfma(P, u1, Qm * s1)));
        }
    }

    // ---- wires 10,11: DPP partners (state bits 1,0), packed update ----
#pragma unroll
    for (int wq = 10; wq <= 11; ++wq) {
        COEFFS(wq);
        const int pb = 11 - wq;                 // 1 or 0
        const int side = (ln >> pb) & 1;
        const float sq = side ? -q : q;
        const float sr = side ? r : -r;
        const f32x2 P={p,p}, Sq={sq,-sq}, Sr={sr,sr}, Tv={t,-t};
#pragma unroll
        for (int l = 0; l < 16; ++l) {
            const f32x2 m = a[l];
            f32x2 pp;
            pp.x = (pb == 0) ? dpp_xor1(m.x) : dpp_xor2(m.x);
            pp.y = (pb == 0) ? dpp_xor1(m.y) : dpp_xor2(m.y);
            a[l] = pkfma(P, m, pkfma(Sq, swp(m), pkfma(Sr, pp, Tv * swp(pp))));
        }
    }

    // ---- transpose: swap state bits [11:8]<->[5:2], chunked by wave-pairs ----
    // chunk c: waves {2c, 2c+1} stage all 16 regs into 2048-entry buffer and read back.
#pragma unroll
    for (int c = 0; c < 2; ++c) {
        if ((w >> 1) == c) {
#pragma unroll
            for (int l = 0; l < 16; ++l)
                B2[(l << 7) | ((w & 1) << 6) | ((ln ^ (l << 2)) & 63)] = a[l];
        }
        __syncthreads();
        if ((w >> 1) == c) {
            const int lo = (ln >> 2) & 15;      // old reg index now in lane bits
#pragma unroll
            for (int l2 = 0; l2 < 16; ++l2) {
                const int la = (((l2 << 2) | (ln & 3)) ^ (lo << 2)) & 63;
                a[l2] = B2[(lo << 7) | ((w & 1) << 6) | la];
            }
        }
        __syncthreads();                        // buffer free for next chunk/phase
    }
    // layout 2: reg l2 holds amp s = ((ln>>2)&15)<<8 | w<<6 | l2<<2 | (ln&3)

    // ---- wires 6..9: now reg-local, packed butterflies ----
#pragma unroll
    for (int wq = 6; wq < 10; ++wq) {
        COEFFS(wq);
        const f32x2 P={p,p}, Q={q,-q}, Qm={-q,q}, R={r,r}, Rm={-r,-r}, T={t,-t};
        const int bit = 1 << (9 - wq);
#pragma unroll
        for (int l0 = 0; l0 < 16; ++l0) {
            if (l0 & bit) continue;
            const int l1 = l0 | bit;
            const f32x2 u0 = a[l0], u1 = a[l1], s0 = swp(u0), s1 = swp(u1);
            a[l0] = pkfma(P, u0, pkfma(Q, s0, pkfma(Rm, u1, T * s1)));
            a[l1] = pkfma(R, u0, pkfma(T, s0, pkfma(P, u1, Qm * s1)));
        }
    }

    // ---- wires 4,5: cross-wave exchange, chunked by reg halves (16 KB) ----
#pragma unroll
    for (int wq = 4; wq <= 5; ++wq) {
        COEFFS(wq);
        const int wmask = (wq == 4) ? 2 : 1;
        const int side  = (w & wmask) ? 1 : 0;   // uniform per wave
        const float sq = side ? -q : q;
        const float sr = side ? r : -r;
        const f32x2 P={p,p}, Sq={sq,-sq}, Sr={sr,sr}, Tv={t,-t};
        const int pw = w ^ wmask;
#pragma unroll
        for (int c2 = 0; c2 < 2; ++c2) {
            // buffer free: trailing barrier of previous phase/chunk
#pragma unroll
            for (int rr = 0; rr < 8; ++rr) {
                const int l = (c2 << 3) | rr;
                B2[(rr << 8) | (w << 6) | ln] = a[l];
            }
            __syncthreads();
#pragma unroll
            for (int rr = 0; rr < 8; ++rr) {
                const int l = (c2 << 3) | rr;
                const f32x2 pp = B2[(rr << 8) | (pw << 6) | ln];
                const f32x2 m = a[l];
                a[l] = pkfma(P, m, pkfma(Sq, swp(m), pkfma(Sr, pp, Tv * swp(pp))));
            }
            __syncthreads();                     // reads done before buffer reuse
        }
    }

    // ---- fused probs + Gray scatter (no p2[] array) + block sum ----
    float s2 = 0.f;
    {
        const int hi = ((ln >> 2) & 15) << 8;
#pragma unroll
        for (int l2 = 0; l2 < 16; ++l2) {
            const float pr2 = fmaf(a[l2].x, a[l2].x, a[l2].y * a[l2].y);
            s2 += pr2;
            const int sdx = hi | (w << 6) | (l2 << 2) | (ln & 3);
            const int g   = sdx ^ (sdx >> 1);    // CNOT cascade = Gray remap
            buf[g ^ (((g >> 8) & 7) << 2)] = pr2;
        }
    }
#pragma unroll
    for (int m = 32; m; m >>= 1) s2 += __shfl_xor(s2, m, 64);
    if (ln == 0) bsum[w] = s2;
    __syncthreads();                             // scatter + bsum visible

    const float ps = bsum[0] + bsum[1] + bsum[2] + bsum[3];
    float* __restrict__ orow = out + ((size_t)row << 12);
    if (ps > EPSF) {
        const float sc = 1.0f / ps;
#pragma unroll
        for (int v = 0; v < 4; ++v) {
            const int k   = (w << 10) | (v << 8) | (ln << 2);
            const int idx = k ^ (((k >> 8) & 7) << 2);   // same XOR as scatter
            float4 d = *reinterpret_cast<const float4*>(&buf[idx]);
            d.x *= sc; d.y *= sc; d.z *= sc; d.w *= sc;
            *reinterpret_cast<float4*>(&orow[k]) = d;
        }
    } else {
        const float u = 1.0f / 4096.0f;
        const float4 d = make_float4(u, u, u, u);
#pragma unroll
        for (int v = 0; v < 4; ++v) {
            const int k = (w << 10) | (v << 8) | (ln << 2);
            *reinterpret_cast<float4*>(&orow[k]) = d;
        }
    }
}

extern "C" void kernel_launch(void* const* d_in, const int* in_sizes, int n_in,
                              void* d_out, int out_size, void* d_ws, size_t ws_size,
                              hipStream_t stream) {
    const float* x  = (const float*)d_in[0];   // (2048, 4096) f32
    const float* qw = (const float*)d_in[1];   // (1, 12, 3) f32
    float* out = (float*)d_out;                // (2048, 4096) f32
    qdense_kernel<<<2048, 256, 0, stream>>>(x, qw, out);
}